// Round 11
// baseline (134.595 us; speedup 1.0000x reference)
//
#include <hip/hip_runtime.h>

// rmsdLoss via associative affine scan — one wave per chain, CHUNK=16.
// R11 = R10 + 4-way ILP inside phase 1: the 16-step dependent xstepP chain
// (R10's longest serial segment; warm replays proved the kernel is
// stall-bound, not memory-bound) becomes 4 independent 4-step sub-chains
// composed with 3 xcombines + 9-FMA translation fixups (associativity).
//
// LDS: P_j = l*what_j packed per k-slab: [k][0..65] Px fp32 (lane ln at [ln]),
// [k][66..131] (Py,Pz) bf16x2. 16.9 KB both chains. Step algebra (verified
// R8-R10): q=rsqrt(P.P), h=q*P, ist=rsqrt(hy^2+hz^2) [cancellation-free st];
// u=M*P; t+=u; c0'=q*u; c1'=ist*(hx*c0'-c0); c2'=ist*(hy*c2-hz*c1).
// Block = 128 thr = 2 waves: wv0 = pred (clipped), wv1 = targ; lane ln owns
// steps [16ln,16ln+16). 6-level shuffle scan -> exclusive prefix E; fold
// (F0,a2) -> G; positions p_k = G.t + G.M*tl[k] (snapshot, no replay).
// Pred positions cross via pitch-49 pos buffer aliasing the dead P arena.

#define LROW  4087
#define NSTEP 1021
#define NROW  2048
#define CHUNK 16
#define SLAB  132                // 66 Px + 66 PyPz per k
#define EPSF  1e-6f
#define INVMEAN (1.0f / (2048.0f * 1024.0f * 3.0f))

__device__ __forceinline__ float frcp(float x){ return __builtin_amdgcn_rcpf(x); }
__device__ __forceinline__ float frsq(float x){ return __builtin_amdgcn_rsqf(x); }

__device__ __forceinline__ unsigned pk_bf16(float y, float z){
  unsigned by = __float_as_uint(y);
  by = (by + 0x7FFFu + ((by >> 16) & 1u)) >> 16;          // rne -> low half
  unsigned bz = __float_as_uint(z);
  bz = (bz + 0x7FFFu + ((bz >> 16) & 1u)) & 0xFFFF0000u;  // rne -> high half
  return bz | by;
}

struct Xf { float f[12]; };  // COLUMN-major: f[0..2]=c0, f[3..5]=c1, f[6..8]=c2, f[9..11]=t

__device__ __forceinline__ Xf xident(){
  Xf X;
  X.f[0]=1.f; X.f[1]=0.f; X.f[2]=0.f;
  X.f[3]=0.f; X.f[4]=1.f; X.f[5]=0.f;
  X.f[6]=0.f; X.f[7]=0.f; X.f[8]=1.f;
  X.f[9]=0.f; X.f[10]=0.f; X.f[11]=0.f;
  return X;
}

// A applied first, then B: C.M = A.M*B.M (columns), C.t = A.t + A.M*B.t
__device__ __forceinline__ Xf xcombine(const Xf& A, const Xf& B){
  Xf C;
  #pragma unroll
  for (int c3 = 0; c3 < 12; c3 += 3){
    const float bx = B.f[c3], by = B.f[c3+1], bz = B.f[c3+2];
    C.f[c3]   = A.f[0]*bx + A.f[3]*by + A.f[6]*bz;
    C.f[c3+1] = A.f[1]*bx + A.f[4]*by + A.f[7]*bz;
    C.f[c3+2] = A.f[2]*bx + A.f[5]*by + A.f[8]*bz;
  }
  C.f[9] += A.f[9]; C.f[10] += A.f[10]; C.f[11] += A.f[11];
  return C;
}

__device__ __forceinline__ void xstepP(Xf& X, float Px, float Py, float Pz){
  const float l2 = Px*Px + Py*Py + Pz*Pz;
  const float q  = frsq(l2);
  const float hx = q*Px, hy = q*Py, hz = q*Pz;
  const float ist = frsq(fmaxf(hy*hy + hz*hz, 1e-12f));   // 1/st, cancellation-free
  const float ux = X.f[0]*Px + X.f[3]*Py + X.f[6]*Pz;
  const float uy = X.f[1]*Px + X.f[4]*Py + X.f[7]*Pz;
  const float uz = X.f[2]*Px + X.f[5]*Py + X.f[8]*Pz;
  X.f[9] += ux; X.f[10] += uy; X.f[11] += uz;
  const float n0x = q*ux, n0y = q*uy, n0z = q*uz;
  const float n1x = ist*(hx*n0x - X.f[0]);
  const float n1y = ist*(hx*n0y - X.f[1]);
  const float n1z = ist*(hx*n0z - X.f[2]);
  const float n2x = ist*(hy*X.f[6] - hz*X.f[3]);
  const float n2y = ist*(hy*X.f[7] - hz*X.f[4]);
  const float n2z = ist*(hy*X.f[8] - hz*X.f[5]);
  X.f[0]=n0x; X.f[1]=n0y; X.f[2]=n0z;
  X.f[3]=n1x; X.f[4]=n1y; X.f[5]=n1z;
  X.f[6]=n2x; X.f[7]=n2y; X.f[8]=n2z;
}

__device__ __forceinline__ void xinitP(Xf& X, float Px, float Py, float Pz){
  const float l2 = Px*Px + Py*Py + Pz*Pz;
  const float q  = frsq(l2);
  const float hx = q*Px, hy = q*Py, hz = q*Pz;
  const float s2 = fmaxf(hy*hy + hz*hz, 1e-12f);
  const float ist = frsq(s2);
  const float st  = s2 * ist;
  X.f[0]=hx;        X.f[1]=hy;          X.f[2]=hz;
  X.f[3]=-st;       X.f[4]=hx*hy*ist;   X.f[5]=hx*hz*ist;
  X.f[6]=0.f;       X.f[7]=-hz*ist;     X.f[8]=hy*ist;
  X.f[9]=Px;        X.f[10]=Py;         X.f[11]=Pz;
}

// t' = P.t + P.M * t   (column-major M)
__device__ __forceinline__ void tfix(const Xf& P, float t[3]){
  const float tx = t[0], ty = t[1], tz = t[2];
  t[0] = P.f[9]  + P.f[0]*tx + P.f[3]*ty + P.f[6]*tz;
  t[1] = P.f[10] + P.f[1]*tx + P.f[4]*ty + P.f[7]*tz;
  t[2] = P.f[11] + P.f[2]*tx + P.f[5]*ty + P.f[8]*tz;
}

__global__ void __launch_bounds__(128, 4)
rmsd_kernel(const float* __restrict__ pred, const float* __restrict__ targ,
            float* __restrict__ out){
  __shared__ float Parena[2][CHUNK][SLAB];   // 16.9 KB
  __shared__ float ini[3];                   // pred a1x, a2x, a2y

  const int row = blockIdx.x;
  const int tid = threadIdx.x;
  const int ln  = tid & 63;
  const int wv  = tid >> 6;      // 0 = pred, 1 = targ
  const int j0  = ln * CHUNK;

  const float* __restrict__ vp = pred + (size_t)row * LROW;
  const float* __restrict__ vt = targ + (size_t)row * LROW;

  // early broadcast loads for the fold (own chain)
  const float* vw = wv ? vt : vp;
  const float lw = wv ? 1e30f : 1.0f;
  const float rb0 = fminf(fmaxf(vw[3064], -lw), lw);
  const float rd0 = fminf(fmaxf(vw[2042], -lw), lw);
  const float rb1w= fminf(fmaxf(vw[3065], -lw), lw);

  // ---- staging phase A: batch-load ALL raw inputs (80 independent dwords) ----
  float s0a[16], s1a[16], rda[16], r1a[16], r2a[16];
  #pragma unroll
  for (int i = 0; i < 16; ++i){
    const int j = tid + ((i & 7) << 7);          // 0..1023
    const float* v = (i < 8) ? vp : vt;
    int i1 = 3065 + j; if (i1 > 4086) i1 = 4086; // j>1020 lanes: clamp (unused)
    int i2 = 3066 + j; if (i2 > 4086) i2 = 4086;
    s0a[i] = v[2*j];
    s1a[i] = v[2*j+1];
    rda[i] = v[2043+j];
    r1a[i] = v[i1];
    r2a[i] = v[i2];
  }

  // ---- staging phase B: compute P_j, store Px fp32 + (Py,Pz) bf16x2 ----
  #pragma unroll
  for (int i = 0; i < 16; ++i){
    const int j = tid + ((i & 7) << 7);
    if (j < NSTEP){
      const int c = i >> 3;
      const float cl = c ? 1e30f : 1.0f;     // reference clips pred only
      const float s0  = fminf(fmaxf(s0a[i], -cl), cl);
      const float s1  = fminf(fmaxf(s1a[i], -cl), cl);
      const float rd  = fminf(fmaxf(rda[i], -cl), cl);
      const float rb1 = fminf(fmaxf(r1a[i], -cl), cl);
      const float rb2 = fminf(fmaxf(r2a[i], -cl), cl);
      const float d  = fmaf(rd,  1.75f, 3.25f);
      const float b1 = fmaf(rb1, 1.05f, 1.95f);
      const float b2 = fmaf(rb2, 1.05f, 1.95f);
      float ct = (b1*b1 + b2*b2 - d*d) * frcp(2.0f*b1*b2);
      ct = fminf(fmaxf(ct, -1.0f + EPSF), 1.0f - EPSF);
      const float st = sqrtf(fmaxf(1.0f - ct*ct, 0.0f));
      const float r2 = s0*s0 + s1*s1;
      const bool ok = r2 > 1e-36f;
      const float ir = ok ? frcp(sqrtf(r2)) : 0.0f;
      const float scv = s0 * ir;
      const float ccv = ok ? s1 * ir : 1.0f;
      float* slab = &Parena[c][j & 15][j >> 4];
      slab[0] = -b2 * ct;
      ((unsigned*)slab)[66] = pk_bf16(b2 * st * ccv, b2 * st * scv);
    }
  }
  __syncthreads();

  // ---- phase 1: 4 independent 4-step sub-chains (explicit ILP) ----
  Xf Xs[4];
  float tl[CHUNK][3];
  #pragma unroll
  for (int k = 0; k < 4; ++k){
    #pragma unroll
    for (int s = 0; s < 4; ++s){
      const int kk = 4*s + k;
      const float* base = &Parena[wv][kk][ln];
      const float    Px = base[0];
      const unsigned pz = ((const unsigned*)base)[66];
      const float Py = __uint_as_float(pz << 16);
      const float Pz = __uint_as_float(pz & 0xFFFF0000u);
      if (k == 0)                    xinitP(Xs[s], Px, Py, Pz);   // j0+4s <= 1020 always
      else if (j0 + kk < NSTEP)      xstepP(Xs[s], Px, Py, Pz);
      tl[kk][0]=Xs[s].f[9]; tl[kk][1]=Xs[s].f[10]; tl[kk][2]=Xs[s].f[11];
    }
  }
  // sequential prefix combines with interleaved fixups (short register lifetimes)
  Xf X;
  {
    Xf AB = xcombine(Xs[0], Xs[1]);
    #pragma unroll
    for (int k = 4; k < 8; ++k)  tfix(Xs[0], tl[k]);   // B local -> chunk local
    Xf ABC = xcombine(AB, Xs[2]);
    #pragma unroll
    for (int k = 8; k < 12; ++k) tfix(AB, tl[k]);      // C local -> chunk local
    X = xcombine(ABC, Xs[3]);
    #pragma unroll
    for (int k = 12; k < 16; ++k) tfix(ABC, tl[k]);    // D local -> chunk local
  }

  // ---- in-wave inclusive scan (Hillis-Steele, non-commutative) ----
  #pragma unroll
  for (int off = 1; off < 64; off <<= 1){
    Xf o;
    #pragma unroll
    for (int i = 0; i < 12; ++i) o.f[i] = __shfl_up(X.f[i], off);
    if (ln >= off) X = xcombine(o, X);
  }
  Xf E;
  #pragma unroll
  for (int i = 0; i < 12; ++i) E.f[i] = __shfl_up(X.f[i], 1);
  if (ln == 0) E = xident();

  // ---- fold (F0, a2): G = F0*E.M ; G.t = a2 + F0*E.t ----
  const float bl0 = fmaf(rb0,  1.05f, 1.95f);
  const float d0  = fmaf(rd0,  1.75f, 3.25f);
  const float b1f = fmaf(rb1w, 1.05f, 1.95f);
  float ct0 = (bl0*bl0 + b1f*b1f - d0*d0) * frcp(2.0f*bl0*b1f);
  ct0 = fminf(fmaxf(ct0, -1.0f + EPSF), 1.0f - EPSF);
  const float st0 = sqrtf(fmaxf(1.0f - ct0*ct0, 0.0f));
  const float a1x = bl0;
  const float a2x = bl0 - b1f*ct0;
  const float a2y = b1f*st0;

  Xf G;   // F0 rows: (-ct0,-st0,0),(st0,-ct0,0),(0,0,1) applied to each column + t
  #pragma unroll
  for (int c3 = 0; c3 < 12; c3 += 3){
    const float ex = E.f[c3], ey = E.f[c3+1], ez = E.f[c3+2];
    G.f[c3]   = -ct0*ex - st0*ey;
    G.f[c3+1] =  st0*ex - ct0*ey;
    G.f[c3+2] =  ez;
  }
  G.f[9] += a2x; G.f[10] += a2y;

  // ---- positions p_k = G.t + G.M * tl[k]  (in place) ----
  #pragma unroll
  for (int k = 0; k < CHUNK; ++k) tfix(G, tl[k]);

  __syncthreads();   // P arena dead for BOTH waves -> safe to reuse as pos

  // ---- pred publishes positions into the dead P arena ----
  float* pos = &Parena[0][0][0];   // pitch 49: max 63*49+45+2 = 3134 < 4224
  if (wv == 0){
    #pragma unroll
    for (int k = 0; k < CHUNK; ++k){
      if (j0 + k < NSTEP){
        const int o = ln*49 + 3*k;
        pos[o] = tl[k][0]; pos[o+1] = tl[k][1]; pos[o+2] = tl[k][2];
      }
    }
    if (ln == 0){ ini[0] = a1x; ini[1] = a2x; ini[2] = a2y; }
  }
  __syncthreads();

  // ---- targ wave: diff + reduce ----
  if (wv == 1){
    float acc = 0.0f;
    if (ln == 0){
      const float dx = ini[0] - a1x;   // a1 differs only in x; a0 diff = 0
      const float dy = ini[1] - a2x;   // a2 differs in x,y (z = 0)
      const float dz = ini[2] - a2y;
      acc = dx*dx + dy*dy + dz*dz;
    }
    #pragma unroll
    for (int k = 0; k < CHUNK; ++k){
      if (j0 + k < NSTEP){
        const int o = ln*49 + 3*k;
        const float dx = pos[o]   - tl[k][0];
        const float dy = pos[o+1] - tl[k][1];
        const float dz = pos[o+2] - tl[k][2];
        acc = fmaf(dx, dx, acc);
        acc = fmaf(dy, dy, acc);
        acc = fmaf(dz, dz, acc);
      }
    }
    #pragma unroll
    for (int off = 32; off > 0; off >>= 1) acc += __shfl_down(acc, off);
    if (ln == 0) atomicAdd(out, acc * INVMEAN);
  }
}

extern "C" void kernel_launch(void* const* d_in, const int* in_sizes, int n_in,
                              void* d_out, int out_size, void* d_ws, size_t ws_size,
                              hipStream_t stream) {
  const float* pred = (const float*)d_in[0];
  const float* targ = (const float*)d_in[1];
  float* out = (float*)d_out;

  hipMemsetAsync(d_out, 0, sizeof(float), stream);
  rmsd_kernel<<<NROW, 128, 0, stream>>>(pred, targ, out);
}